// Round 3
// baseline (255.564 us; speedup 1.0000x reference)
//
#include <hip/hip_runtime.h>
#include <hip/hip_cooperative_groups.h>

namespace cg = cooperative_groups;

// Problem constants: B=8, N=16384, S=1024, T=2, D=3
#define NPTS 16384
#define SPTS 1024

// Single cooperative kernel, 768 blocks x 256 threads:
//   phase 0: init accum + minarr (no memsets needed)
//   phase 1: blocks 0..63 also do consistency MSE;
//            blocks 0..383   = pass A (per gt point, min over 1024 structure pts), G=4
//            blocks 384..767 = pass B (per structure pt, min over gt chunk of 1024), G=4
//   phase 2: block 0 reduces minarr + accum -> out[0]
__global__ __launch_bounds__(256) void uber_kernel(
    const float* __restrict__ gt,   // [8,16384,3]
    const float* __restrict__ sp,   // [8,1024,3]
    const float* __restrict__ tgt,  // [16,16384,3]
    const float* __restrict__ tsp,  // [16,1024,3]
    const float* __restrict__ tm,   // [2,3,3]
    float* __restrict__ accum,
    unsigned int* __restrict__ minarr,  // [24*1024]
    float* __restrict__ out)
{
    cg::grid_group grid = cg::this_grid();
    const int bid = blockIdx.x;
    const int tid = threadIdx.x;

    __shared__ float4 s_ref[1024];  // 16 KB

    // ---- phase 0: init workspace (harness poisons ws each launch) ----
    if (bid == 0 && tid == 0) accum[0] = 0.f;
    if (bid < 96) minarr[bid * 256 + tid] = 0x7F7F7F7Fu;  // ~3.39e38
    grid.sync();

    // ---- consistency MSE, folded into the first 64 blocks ----
    if (bid < 64) {
        int idx = bid * 256 + tid;     // over (t,b,s) = 2*8*1024
        int t = idx >> 13;
        int bs = idx & 8191;
        const float* p = sp + (size_t)bs * 3;
        float x = p[0], y = p[1], z = p[2];
        const float* m = tm + t * 9;   // trans[t,d,e] at t*9 + d*3 + e
        const float* q = tsp + (size_t)idx * 3;
        float acc = 0.f;
#pragma unroll
        for (int e = 0; e < 3; e++) {
            float v = fmaf(x, m[e], fmaf(y, m[3 + e], z * m[6 + e]));
            float d = v - q[e];
            acc = fmaf(d, d, acc);
        }
        for (int o = 32; o > 0; o >>= 1) acc += __shfl_down(acc, o, 64);
        if ((tid & 63) == 0)
            atomicAdd(accum, acc * (1000.f / (2.f * 8.f * 1024.f * 3.f)));
    }

    if (bid < 384) {
        // ---- pass A: block = (bb, 1024-query tile), refs = all 1024 in LDS ----
        int bb = bid >> 4, tile = bid & 15;
        const float* refp = (bb < 8) ? sp + (size_t)bb * SPTS * 3
                                     : tsp + (size_t)(bb - 8) * SPTS * 3;
        const float* qp   = (bb < 8) ? gt + (size_t)bb * NPTS * 3
                                     : tgt + (size_t)(bb - 8) * NPTS * 3;
        for (int i = tid; i < 1024; i += 256) {
            float x = refp[i * 3], y = refp[i * 3 + 1], z = refp[i * 3 + 2];
            s_ref[i] = make_float4(x, y, z, x * x + y * y + z * z);
        }
        __syncthreads();

        float qx[4], qy[4], qz[4], qs[4], mn[4];
#pragma unroll
        for (int g = 0; g < 4; g++) {
            int q = tile * 1024 + g * 256 + tid;
            float x = qp[q * 3], y = qp[q * 3 + 1], z = qp[q * 3 + 2];
            qx[g] = -2.f * x; qy[g] = -2.f * y; qz[g] = -2.f * z;
            qs[g] = x * x + y * y + z * z;
            mn[g] = 1e30f;
        }
#pragma unroll 8
        for (int j = 0; j < 1024; j++) {
            float4 s = s_ref[j];  // wave-uniform -> LDS broadcast
#pragma unroll
            for (int g = 0; g < 4; g++) {
                float d = fmaf(qx[g], s.x, fmaf(qy[g], s.y, fmaf(qz[g], s.z, s.w)));
                mn[g] = fminf(mn[g], d);
            }
        }
        float v = (qs[0] + mn[0]) + (qs[1] + mn[1]) + (qs[2] + mn[2]) + (qs[3] + mn[3]);
        for (int o = 32; o > 0; o >>= 1) v += __shfl_down(v, o, 64);
        if ((tid & 63) == 0) {
            float scale = (bb < 8) ? 1.f / (2.f * 3.f * 8.f * 16384.f)
                                   : 1.f / (2.f * 3.f * 16.f * 16384.f);
            atomicAdd(accum, v * scale);
        }
    } else {
        // ---- pass B: block = (bb, 1024-ref chunk), queries = all 1024, G=4 ----
        int idx = bid - 384;
        int bb = idx >> 4, chunk = idx & 15;
        const float* refp = (bb < 8) ? gt + (size_t)bb * NPTS * 3
                                     : tgt + (size_t)(bb - 8) * NPTS * 3;
        const float* qp   = (bb < 8) ? sp + (size_t)bb * SPTS * 3
                                     : tsp + (size_t)(bb - 8) * SPTS * 3;
        for (int i = tid; i < 1024; i += 256) {
            int j = chunk * 1024 + i;
            float x = refp[j * 3], y = refp[j * 3 + 1], z = refp[j * 3 + 2];
            s_ref[i] = make_float4(x, y, z, x * x + y * y + z * z);
        }
        __syncthreads();

        float qx[4], qy[4], qz[4], qs[4], mn[4];
#pragma unroll
        for (int g = 0; g < 4; g++) {
            int q = g * 256 + tid;
            float x = qp[q * 3], y = qp[q * 3 + 1], z = qp[q * 3 + 2];
            qx[g] = -2.f * x; qy[g] = -2.f * y; qz[g] = -2.f * z;
            qs[g] = x * x + y * y + z * z;
            mn[g] = 1e30f;
        }
#pragma unroll 8
        for (int j = 0; j < 1024; j++) {
            float4 s = s_ref[j];
#pragma unroll
            for (int g = 0; g < 4; g++) {
                float d = fmaf(qx[g], s.x, fmaf(qy[g], s.y, fmaf(qz[g], s.z, s.w)));
                mn[g] = fminf(mn[g], d);
            }
        }
#pragma unroll
        for (int g = 0; g < 4; g++) {
            int q = g * 256 + tid;
            float val = fmaxf(qs[g] + mn[g], 0.f);  // nonneg so uint-ordered min works
            atomicMin(&minarr[bb * SPTS + q], __float_as_uint(val));
        }
    }

    grid.sync();

    // ---- phase 2: finalize (block 0) ----
    if (bid == 0) {
        float s = 0.f;
        for (int i = tid; i < 24 * 1024; i += 256) {
            float v = __uint_as_float(minarr[i]);
            int bbx = i >> 10;
            float scale = (bbx < 8) ? 1.f / (2.f * 3.f * 8.f * 1024.f)
                                    : 1.f / (2.f * 3.f * 16.f * 1024.f);
            s = fmaf(v, scale, s);
        }
        for (int o = 32; o > 0; o >>= 1) s += __shfl_down(s, o, 64);
        __shared__ float fsum[4];
        if ((tid & 63) == 0) fsum[tid >> 6] = s;
        __syncthreads();
        if (tid == 0) out[0] = accum[0] + fsum[0] + fsum[1] + fsum[2] + fsum[3];
    }
}

extern "C" void kernel_launch(void* const* d_in, const int* in_sizes, int n_in,
                              void* d_out, int out_size, void* d_ws, size_t ws_size,
                              hipStream_t stream) {
    const float* gt  = (const float*)d_in[0];  // gt_points [8,16384,3]
    const float* sp  = (const float*)d_in[1];  // structure_points [8,1024,3]
    const float* tgt = (const float*)d_in[2];  // transed_gt_points [2,8,16384,3]
    const float* tsp = (const float*)d_in[3];  // transed_structure_points [2,8,1024,3]
    const float* tm  = (const float*)d_in[4];  // trans_mats [2,3,3]
    float* out = (float*)d_out;

    float* accum = (float*)d_ws;
    unsigned int* minarr = (unsigned int*)((char*)d_ws + 64);

    void* args[] = { (void*)&gt, (void*)&sp, (void*)&tgt, (void*)&tsp, (void*)&tm,
                     (void*)&accum, (void*)&minarr, (void*)&out };
    hipLaunchCooperativeKernel((const void*)uber_kernel, dim3(768), dim3(256),
                               args, 0, stream);
}

// Round 5
// 164.273 us; speedup vs baseline: 1.5557x; 1.5557x over previous
//
#include <hip/hip_runtime.h>

// Problem constants: B=8, N=16384, S=1024, T=2, D=3
#define NPTS 16384
#define SPTS 1024

// Fused kernel, 640 blocks x 256 threads, regular launch (no grid.sync):
//  bid [0,192)   : pass A — bb=bid/8, qtile=bid%8 (2048 queries), all 1024 refs in LDS,
//                  G=8 queries/thread, full min in-thread -> wave-reduce -> atomicAdd.
//  bid [192,576) : pass B — bb, chunk of 1024 gt refs in LDS; waves split j-range
//                  (tid<128: j<512, else j>=512), G=8 over all 1024 queries;
//                  halves merged via LDS, then one atomicMin per query per block.
//  bid [576,640) : consistency MSE -> atomicAdd.
__global__ __launch_bounds__(256) void fused_kernel(
    const float* __restrict__ gt,   // [8,16384,3]
    const float* __restrict__ sp,   // [8,1024,3]
    const float* __restrict__ tgt,  // [16,16384,3]
    const float* __restrict__ tsp,  // [16,1024,3]
    const float* __restrict__ tm,   // [2,3,3]
    float* __restrict__ accum,
    unsigned int* __restrict__ minarr)  // [24*1024], pre-init 0x7F bytes
{
    const int bid = blockIdx.x;
    const int tid = threadIdx.x;
    __shared__ float4 s_ref[1024];  // 16 KB

    if (bid < 192) {
        // ---------------- pass A ----------------
        int bb = bid >> 3, qtile = bid & 7;
        const float* refp = (bb < 8) ? sp + (size_t)bb * SPTS * 3
                                     : tsp + (size_t)(bb - 8) * SPTS * 3;
        const float* qp   = (bb < 8) ? gt + (size_t)bb * NPTS * 3
                                     : tgt + (size_t)(bb - 8) * NPTS * 3;
        for (int i = tid; i < 1024; i += 256) {
            float x = refp[i * 3], y = refp[i * 3 + 1], z = refp[i * 3 + 2];
            s_ref[i] = make_float4(x, y, z, x * x + y * y + z * z);
        }
        __syncthreads();

        float qx[8], qy[8], qz[8], qs[8], mn[8];
#pragma unroll
        for (int g = 0; g < 8; g++) {
            int q = qtile * 2048 + g * 256 + tid;
            float x = qp[q * 3], y = qp[q * 3 + 1], z = qp[q * 3 + 2];
            qx[g] = -2.f * x; qy[g] = -2.f * y; qz[g] = -2.f * z;
            qs[g] = x * x + y * y + z * z;
            mn[g] = 1e30f;
        }
#pragma unroll 4
        for (int j = 0; j < 1024; j++) {
            float4 s = s_ref[j];  // wave-uniform broadcast
#pragma unroll
            for (int g = 0; g < 8; g++) {
                float d = fmaf(qx[g], s.x, fmaf(qy[g], s.y, fmaf(qz[g], s.z, s.w)));
                mn[g] = fminf(mn[g], d);
            }
        }
        float v = 0.f;
#pragma unroll
        for (int g = 0; g < 8; g++) v += qs[g] + mn[g];
        for (int o = 32; o > 0; o >>= 1) v += __shfl_down(v, o, 64);
        if ((tid & 63) == 0) {
            float scale = (bb < 8) ? 1.f / (2.f * 3.f * 8.f * 16384.f)
                                   : 1.f / (2.f * 3.f * 16.f * 16384.f);
            atomicAdd(accum, v * scale);
        }
    } else if (bid < 576) {
        // ---------------- pass B ----------------
        int idx = bid - 192;
        int bb = idx >> 4, chunk = idx & 15;
        const float* refp = (bb < 8) ? gt + (size_t)bb * NPTS * 3
                                     : tgt + (size_t)(bb - 8) * NPTS * 3;
        const float* qp   = (bb < 8) ? sp + (size_t)bb * SPTS * 3
                                     : tsp + (size_t)(bb - 8) * SPTS * 3;
        for (int i = tid; i < 1024; i += 256) {
            int j = chunk * 1024 + i;
            float x = refp[j * 3], y = refp[j * 3 + 1], z = refp[j * 3 + 2];
            s_ref[i] = make_float4(x, y, z, x * x + y * y + z * z);
        }
        __syncthreads();

        const int qt = tid & 127;          // query lane
        const int half = tid >> 7;         // 0: j<512, 1: j>=512
        float qx[8], qy[8], qz[8], qs[8], mn[8];
#pragma unroll
        for (int g = 0; g < 8; g++) {
            int q = g * 128 + qt;
            float x = qp[q * 3], y = qp[q * 3 + 1], z = qp[q * 3 + 2];
            qx[g] = -2.f * x; qy[g] = -2.f * y; qz[g] = -2.f * z;
            qs[g] = x * x + y * y + z * z;
            mn[g] = 1e30f;
        }
        int j0 = half * 512;
#pragma unroll 4
        for (int jj = 0; jj < 512; jj++) {
            float4 s = s_ref[j0 + jj];
#pragma unroll
            for (int g = 0; g < 8; g++) {
                float d = fmaf(qx[g], s.x, fmaf(qy[g], s.y, fmaf(qz[g], s.z, s.w)));
                mn[g] = fminf(mn[g], d);
            }
        }
        // merge the two j-halves via LDS, then one atomicMin per query
        __syncthreads();
        float* lds_f = (float*)s_ref;
        if (half == 1) {
#pragma unroll
            for (int g = 0; g < 8; g++) lds_f[g * 128 + qt] = qs[g] + mn[g];
        }
        __syncthreads();
        if (half == 0) {
#pragma unroll
            for (int g = 0; g < 8; g++) {
                int q = g * 128 + qt;
                float val = fminf(qs[g] + mn[g], lds_f[q]);
                val = fmaxf(val, 0.f);  // nonneg so uint-ordered min works
                atomicMin(&minarr[bb * SPTS + q], __float_as_uint(val));
            }
        }
    } else {
        // ---------------- consistency MSE ----------------
        int idx = (bid - 576) * 256 + tid;  // over (t,b,s) = 2*8*1024
        int t = idx >> 13;
        int bs = idx & 8191;
        const float* p = sp + (size_t)bs * 3;
        float x = p[0], y = p[1], z = p[2];
        const float* m = tm + t * 9;
        const float* q = tsp + (size_t)idx * 3;
        float acc = 0.f;
#pragma unroll
        for (int e = 0; e < 3; e++) {
            float v = fmaf(x, m[e], fmaf(y, m[3 + e], z * m[6 + e]));
            float d = v - q[e];
            acc = fmaf(d, d, acc);
        }
        for (int o = 32; o > 0; o >>= 1) acc += __shfl_down(acc, o, 64);
        if ((tid & 63) == 0)
            atomicAdd(accum, acc * (1000.f / (2.f * 8.f * 1024.f * 3.f)));
    }
}

__global__ __launch_bounds__(256) void finalize_kernel(
    const unsigned int* __restrict__ minarr,
    const float* __restrict__ accum,
    float* __restrict__ out)
{
    float s = 0.f;
    for (int i = threadIdx.x; i < 24 * 1024; i += 256) {
        float v = __uint_as_float(minarr[i]);
        int bb = i >> 10;
        float scale = (bb < 8) ? 1.f / (2.f * 3.f * 8.f * 1024.f)
                               : 1.f / (2.f * 3.f * 16.f * 1024.f);
        s = fmaf(v, scale, s);
    }
    for (int o = 32; o > 0; o >>= 1) s += __shfl_down(s, o, 64);
    __shared__ float fsum[4];
    if ((threadIdx.x & 63) == 0) fsum[threadIdx.x >> 6] = s;
    __syncthreads();
    if (threadIdx.x == 0) out[0] = accum[0] + fsum[0] + fsum[1] + fsum[2] + fsum[3];
}

extern "C" void kernel_launch(void* const* d_in, const int* in_sizes, int n_in,
                              void* d_out, int out_size, void* d_ws, size_t ws_size,
                              hipStream_t stream) {
    const float* gt  = (const float*)d_in[0];  // gt_points [8,16384,3]
    const float* sp  = (const float*)d_in[1];  // structure_points [8,1024,3]
    const float* tgt = (const float*)d_in[2];  // transed_gt_points [2,8,16384,3]
    const float* tsp = (const float*)d_in[3];  // transed_structure_points [2,8,1024,3]
    const float* tm  = (const float*)d_in[4];  // trans_mats [2,3,3]
    float* out = (float*)d_out;

    float* accum = (float*)d_ws;
    unsigned int* minarr = (unsigned int*)((char*)d_ws + 64);

    hipMemsetAsync(accum, 0, 64, stream);
    hipMemsetAsync(minarr, 0x7F, 24 * 1024 * sizeof(unsigned int), stream);

    fused_kernel<<<640, 256, 0, stream>>>(gt, sp, tgt, tsp, tm, accum, minarr);
    finalize_kernel<<<1, 256, 0, stream>>>(minarr, accum, out);
}